// Round 2
// baseline (1426.865 us; speedup 1.0000x reference)
//
#include <hip/hip_runtime.h>
#include <math.h>

#define HH 1024
#define AA 180
#define BB 16
#define NCOL (BB*AA)          // 2880 (b,angle) columns
#define GUARD 48              // zero guard floats each side of a filtered row
#define RS 1120               // row stride: 48 | 1024 | 48
#define PI_D 3.14159265358979323846

// ws float-offsets
#define OFF_CG   0            // 512 filter coeffs
#define OFF_CST  512          // float4[180]: (512cos, 512sin, 0, 0)
#define OFF_XAF  1232         // NCOL*RS filtered rows (guarded), 16B-aligned

typedef float f2 __attribute__((ext_vector_type(2)));

__device__ __forceinline__ float fractf_(float x) {
#if __has_builtin(__builtin_amdgcn_fractf)
    return __builtin_amdgcn_fractf(x);   // v_fract_f32: x - floor(x)
#else
    return x - floorf(x);
#endif
}

// ---------------- tables ----------------
__global__ __launch_bounds__(512) void k_tables(float* __restrict__ ws) {
    int t = threadIdx.x;
    if (t < 512) {
        double d = 2.0 * t + 1.0;
        ws[OFF_CG + t] = (float)(-2.0 / (PI_D * PI_D * d * d));
    }
    if (t < AA) {
        float thf = (float)t * 0.017453292519943295f;  // fp32(pi/180)
        double th = (double)thf;
        float4* cst4 = (float4*)(ws + OFF_CST);
        cst4[t] = make_float4((float)(512.0 * cos(th)), (float)(512.0 * sin(th)), 0.f, 0.f);
    }
}

// ---------------- fused angle-interp + ramp filter ----------------
// One wave per (b,angle-out) column. Staging does the 2-tap angle interp
// (linear ops commute with the filter). Output scaled by pi/360 and written
// into a guarded row: 48 zeros | 1024 filtered | 48 zeros.
__global__ __launch_bounds__(64) void k_filter(const float* __restrict__ x,
                                               const float* __restrict__ cg,
                                               float* __restrict__ xaf) {
    __shared__ float xsp[3264];        // logical [0..3070], swizzled q->q+(q>>4)
    int t = threadIdx.x;
    int col = blockIdx.x;
    int b = col / AA, a = col - b * AA;

    float4* z4 = (float4*)xsp;
    #pragma unroll
    for (int i = t; i < 816; i += 64) z4[i] = make_float4(0.f, 0.f, 0.f, 0.f);
    __syncthreads();

    // angle interp weights (matches reference _backproject's xa)
    float ixf = (float)a * (float)(180.0/179.0) - 0.5f;
    float fl = floorf(ixf);
    int i0 = (int)fl;
    float fx = ixf - fl;
    float w0 = (i0 >= 0)      ? (1.0f - fx) : 0.0f;
    float w1 = (i0 + 1 < AA)  ? fx          : 0.0f;
    int c0 = max(i0, 0);
    int c1 = min(i0 + 1, AA - 1);
    const float* xb = x + (size_t)b * HH * AA;
    for (int i = t; i < HH; i += 64) {
        float v = w0 * xb[i * AA + c0] + w1 * xb[i * AA + c1];
        int q = 1024 + i;
        xsp[q + (q >> 4)] = v;         // lane stride 17 -> conflict-free
    }
    __syncthreads();

    int pp = 17 * t;                   // swizzled base of this thread's p=16t
    float acc[16], Lw[16], Rw[16];
    #pragma unroll
    for (int m = 0; m < 16; ++m) {
        int f = 1024 + m;
        acc[m] = 0.5f * xsp[pp + f + (f >> 4)];
    }
    #pragma unroll
    for (int m = 0; m < 16; ++m) {
        int f = 1 + m;                 // x[p+m-1023]
        Lw[(m + 1) & 15] = xsp[pp + f + (f >> 4)];
        int g = 2047 + m;              // x[p+m+1023]
        Rw[(m - 1) & 15] = xsp[pp + g + (g >> 4)];
    }

    for (int it0 = 0; it0 < 512; it0 += 8) {
        #pragma unroll
        for (int u = 0; u < 8; ++u) {
            int it = it0 + u;          // d = 1023 - 2*it
            float cv = cg[511 - it];   // uniform -> s_load
            #pragma unroll
            for (int m = 0; m < 16; ++m) {
                acc[m] = fmaf(cv, Lw[(m + 2*u + 1) & 15] + Rw[(m - 2*u - 1) & 15], acc[m]);
            }
            int fL  = 2*it + 17;
            Lw[(2*u + 1) & 15] = xsp[pp + fL  + (fL  >> 4)];
            int fL2 = 2*it + 18;
            Lw[(2*u + 2) & 15] = xsp[pp + fL2 + (fL2 >> 4)];
            int fR  = 2045 - 2*it;
            Rw[(13 - 2*u) & 15] = xsp[pp + fR  + (fR  >> 4)];
            int fR2 = 2046 - 2*it;
            Rw[(14 - 2*u) & 15] = xsp[pp + fR2 + (fR2 >> 4)];
        }
    }

    const float SC = (float)(PI_D / 360.0);   // fold pi/(2A) into the filter
    float* rb = xaf + (size_t)col * RS;
    // zero guards: offsets [0,48) and [1072,1120) as float4s
    if (t < 12)            ((float4*)rb)[t]              = make_float4(0.f,0.f,0.f,0.f);
    else if (t < 24)       ((float4*)rb)[268 + (t - 12)] = make_float4(0.f,0.f,0.f,0.f);
    float4* o4 = (float4*)(rb + GUARD + 16 * t);
    #pragma unroll
    for (int m4 = 0; m4 < 4; ++m4)
        o4[m4] = make_float4(acc[4*m4]*SC, acc[4*m4+1]*SC, acc[4*m4+2]*SC, acc[4*m4+3]*SC);
}

// ---------------- backprojection: 2x2 pixels per thread, packed f32 ----------------
__global__ __launch_bounds__(256) void k_bproj(const float* __restrict__ ws,
                                               const float* __restrict__ xaf,
                                               float* __restrict__ out) {
    const float4* cst4 = (const float4*)(ws + OFF_CST);
    int tx = threadIdx.x, ty = threadIdx.y;
    int bx = blockIdx.x, by = blockIdx.y, b = blockIdx.z;
    int xg = bx * 32 + 2 * tx;
    int yg = by * 32 + 2 * ty;
    const float DEL = (float)(2.0 / 1023.0);
    // bit-exact jnp.linspace replication (mul then add, no contraction)
    float ux0 = __fadd_rn(__fmul_rn((float)xg,       DEL), -1.0f);
    float ux1 = __fadd_rn(__fmul_rn((float)(xg + 1), DEL), -1.0f);
    float uy0 = __fadd_rn(__fmul_rn((float)yg,       DEL), -1.0f);
    float uy1 = __fadd_rn(__fmul_rn((float)(yg + 1), DEL), -1.0f);

    // tile classification (32x32 tile) for the fully-outside early exit
    float cx0 = __fadd_rn(__fmul_rn((float)(bx*32),      DEL), -1.0f);
    float cx1 = __fadd_rn(__fmul_rn((float)(bx*32 + 31), DEL), -1.0f);
    float cy0 = __fadd_rn(__fmul_rn((float)(by*32),      DEL), -1.0f);
    float cy1 = __fadd_rn(__fmul_rn((float)(by*32 + 31), DEL), -1.0f);
    float minax = (cx0 <= 0.f && cx1 >= 0.f) ? 0.f : fminf(fabsf(cx0), fabsf(cx1));
    float minay = (cy0 <= 0.f && cy1 >= 0.f) ? 0.f : fminf(fabsf(cy0), fabsf(cy1));
    float rmin2 = minax * minax + minay * minay;

    size_t o0 = ((size_t)b << 20) + ((size_t)yg << 10) + (size_t)xg;
    float2* po0 = (float2*)(out + o0);
    float2* po1 = (float2*)(out + o0 + 1024);

    if (rmin2 > 1.000001f) {
        *po0 = make_float2(0.f, 0.f);
        *po1 = make_float2(0.f, 0.f);
        return;
    }

    // row base = guard origin; +48 bias in the base keeps all indices >= 0
    const float* rp0 = xaf + (size_t)b * (AA * RS);
    const float BIAS = 511.5f + (float)GUARD;   // 559.5
    f2 ux2 = {ux0, ux1};
    float nuy0 = -uy0, nuy1 = -uy1;
    f2 acc0 = {0.f, 0.f}, acc1 = {0.f, 0.f};

    #pragma unroll 2
    for (int a = 0; a < AA; ++a) {
        float4 cs = cst4[a];                       // uniform -> s_load_dwordx4
        float b0 = fmaf(nuy0, cs.y, BIAS);
        float b1 = fmaf(nuy1, cs.y, BIAS);
        f2 c2 = {cs.x, cs.x};
        f2 B0 = {b0, b0};
        f2 B1 = {b1, b1};
        f2 P0 = __builtin_elementwise_fma(ux2, c2, B0);   // v_pk_fma_f32
        f2 P1 = __builtin_elementwise_fma(ux2, c2, B1);
        const float* r = rp0 + a * RS;
        int j0 = (int)P0.x, j1 = (int)P0.y;        // trunc == floor (P >= 0)
        int j2 = (int)P1.x, j3 = (int)P1.y;
        f2 G0 = {fractf_(P0.x), fractf_(P0.y)};
        f2 G1 = {fractf_(P1.x), fractf_(P1.y)};
        f2 A0 = {r[j0],     r[j1]};
        f2 V0 = {r[j0 + 1], r[j1 + 1]};
        f2 A1 = {r[j2],     r[j3]};
        f2 V1 = {r[j2 + 1], r[j3 + 1]};
        acc0 = __builtin_elementwise_fma(G0, V0 - A0, acc0 + A0);
        acc1 = __builtin_elementwise_fma(G1, V1 - A1, acc1 + A1);
    }

    // bit-exact circle mask per pixel (scale already folded into filter)
    float r00 = __fadd_rn(__fmul_rn(ux0, ux0), __fmul_rn(uy0, uy0));
    float r10 = __fadd_rn(__fmul_rn(ux1, ux1), __fmul_rn(uy0, uy0));
    float r01 = __fadd_rn(__fmul_rn(ux0, ux0), __fmul_rn(uy1, uy1));
    float r11 = __fadd_rn(__fmul_rn(ux1, ux1), __fmul_rn(uy1, uy1));
    *po0 = make_float2((r00 <= 1.0f) ? acc0.x : 0.f, (r10 <= 1.0f) ? acc0.y : 0.f);
    *po1 = make_float2((r01 <= 1.0f) ? acc1.x : 0.f, (r11 <= 1.0f) ? acc1.y : 0.f);
}

extern "C" void kernel_launch(void* const* d_in, const int* in_sizes, int n_in,
                              void* d_out, int out_size, void* d_ws, size_t ws_size,
                              hipStream_t stream) {
    const float* x = (const float*)d_in[0];
    float* out = (float*)d_out;
    float* ws = (float*)d_ws;
    float* cg  = ws + OFF_CG;
    float* xaf = ws + OFF_XAF;

    hipLaunchKernelGGL(k_tables, dim3(1), dim3(512), 0, stream, ws);
    hipLaunchKernelGGL(k_filter, dim3(NCOL), dim3(64), 0, stream, x, cg, xaf);
    hipLaunchKernelGGL(k_bproj, dim3(32, 32, BB), dim3(16, 16), 0, stream, ws, xaf, out);
}

// Round 3
// 1286.317 us; speedup vs baseline: 1.1093x; 1.1093x over previous
//
#include <hip/hip_runtime.h>
#include <math.h>

#define HH 1024
#define AA 180
#define BB 16
#define NCOL (BB*AA)          // 2880 (b,angle) columns
#define GUARD 48              // zero guard floats each side of a filtered row
#define RS 1120               // row stride: 48 | 1024 | 48
#define PI_D 3.14159265358979323846

// ws float-offsets
#define OFF_CG   0            // 512 filter coeffs
#define OFF_CST  512          // float2[180]: (512cos, 512sin)
#define OFF_XAF  1232         // NCOL*RS filtered rows (guarded), 16B-aligned

__device__ __forceinline__ float fractf_(float x) {
#if __has_builtin(__builtin_amdgcn_fractf)
    return __builtin_amdgcn_fractf(x);   // v_fract_f32: x - floor(x)
#else
    return x - floorf(x);
#endif
}

// ---------------- tables ----------------
__global__ __launch_bounds__(512) void k_tables(float* __restrict__ ws) {
    int t = threadIdx.x;
    if (t < 512) {
        double d = 2.0 * t + 1.0;
        ws[OFF_CG + t] = (float)(-2.0 / (PI_D * PI_D * d * d));
    }
    if (t < AA) {
        float thf = (float)t * 0.017453292519943295f;  // fp32(pi/180)
        double th = (double)thf;
        float2* cst2 = (float2*)(ws + OFF_CST);
        cst2[t] = make_float2((float)(512.0 * cos(th)), (float)(512.0 * sin(th)));
    }
}

// ---------------- fused angle-interp + ramp filter ----------------
// One wave per (b,angle-out) column. Staging does the 2-tap angle interp
// (linear ops commute with the filter). Output scaled by pi/360 and written
// into a guarded row: 48 zeros | 1024 filtered | 48 zeros.
__global__ __launch_bounds__(64) void k_filter(const float* __restrict__ x,
                                               const float* __restrict__ cg,
                                               float* __restrict__ xaf) {
    __shared__ float xsp[3264];        // logical [0..3070], swizzled q->q+(q>>4)
    int t = threadIdx.x;
    int col = blockIdx.x;
    int b = col / AA, a = col - b * AA;

    float4* z4 = (float4*)xsp;
    #pragma unroll
    for (int i = t; i < 816; i += 64) z4[i] = make_float4(0.f, 0.f, 0.f, 0.f);
    __syncthreads();

    // angle interp weights (matches reference _backproject's xa)
    float ixf = (float)a * (float)(180.0/179.0) - 0.5f;
    float fl = floorf(ixf);
    int i0 = (int)fl;
    float fx = ixf - fl;
    float w0 = (i0 >= 0)      ? (1.0f - fx) : 0.0f;
    float w1 = (i0 + 1 < AA)  ? fx          : 0.0f;
    int c0 = max(i0, 0);
    int c1 = min(i0 + 1, AA - 1);
    const float* xb = x + (size_t)b * HH * AA;
    for (int i = t; i < HH; i += 64) {
        float v = w0 * xb[i * AA + c0] + w1 * xb[i * AA + c1];
        int q = 1024 + i;
        xsp[q + (q >> 4)] = v;         // lane stride 17 -> conflict-free
    }
    __syncthreads();

    int pp = 17 * t;                   // swizzled base of this thread's p=16t
    float acc[16], Lw[16], Rw[16];
    #pragma unroll
    for (int m = 0; m < 16; ++m) {
        int f = 1024 + m;
        acc[m] = 0.5f * xsp[pp + f + (f >> 4)];
    }
    #pragma unroll
    for (int m = 0; m < 16; ++m) {
        int f = 1 + m;                 // x[p+m-1023]
        Lw[(m + 1) & 15] = xsp[pp + f + (f >> 4)];
        int g = 2047 + m;              // x[p+m+1023]
        Rw[(m - 1) & 15] = xsp[pp + g + (g >> 4)];
    }

    for (int it0 = 0; it0 < 512; it0 += 8) {
        #pragma unroll
        for (int u = 0; u < 8; ++u) {
            int it = it0 + u;          // d = 1023 - 2*it
            float cv = cg[511 - it];   // uniform -> s_load
            #pragma unroll
            for (int m = 0; m < 16; ++m) {
                acc[m] = fmaf(cv, Lw[(m + 2*u + 1) & 15] + Rw[(m - 2*u - 1) & 15], acc[m]);
            }
            int fL  = 2*it + 17;
            Lw[(2*u + 1) & 15] = xsp[pp + fL  + (fL  >> 4)];
            int fL2 = 2*it + 18;
            Lw[(2*u + 2) & 15] = xsp[pp + fL2 + (fL2 >> 4)];
            int fR  = 2045 - 2*it;
            Rw[(13 - 2*u) & 15] = xsp[pp + fR  + (fR  >> 4)];
            int fR2 = 2046 - 2*it;
            Rw[(14 - 2*u) & 15] = xsp[pp + fR2 + (fR2 >> 4)];
        }
    }

    const float SC = (float)(PI_D / 360.0);   // fold pi/(2A) into the filter
    float* rb = xaf + (size_t)col * RS;
    // zero guards: offsets [0,48) and [1072,1120) as float4s
    if (t < 12)            ((float4*)rb)[t]              = make_float4(0.f,0.f,0.f,0.f);
    else if (t < 24)       ((float4*)rb)[268 + (t - 12)] = make_float4(0.f,0.f,0.f,0.f);
    float4* o4 = (float4*)(rb + GUARD + 16 * t);
    #pragma unroll
    for (int m4 = 0; m4 < 4; ++m4)
        o4[m4] = make_float4(acc[4*m4]*SC, acc[4*m4+1]*SC, acc[4*m4+2]*SC, acc[4*m4+3]*SC);
}

// ---------------- backprojection: 1 pixel/thread, lean inner loop ----------------
__global__ __launch_bounds__(256, 4) void k_bproj(const float* __restrict__ ws,
                                                  const float* __restrict__ xaf,
                                                  float* __restrict__ out) {
    const float2* cst2 = (const float2*)(ws + OFF_CST);
    int t = threadIdx.x;
    int tx = t & 15, ty = t >> 4;
    int bx = blockIdx.x, by = blockIdx.y, b = blockIdx.z;
    int xg = bx * 16 + tx, yg = by * 16 + ty;
    const float DEL = (float)(2.0 / 1023.0);
    // bit-exact jnp.linspace replication (mul then add, no contraction)
    float ux = __fadd_rn(__fmul_rn((float)xg, DEL), -1.0f);
    float uy = __fadd_rn(__fmul_rn((float)yg, DEL), -1.0f);

    // tile classification for the fully-outside early exit
    float cx0 = __fadd_rn(__fmul_rn((float)(bx*16),      DEL), -1.0f);
    float cx1 = __fadd_rn(__fmul_rn((float)(bx*16 + 15), DEL), -1.0f);
    float cy0 = __fadd_rn(__fmul_rn((float)(by*16),      DEL), -1.0f);
    float cy1 = __fadd_rn(__fmul_rn((float)(by*16 + 15), DEL), -1.0f);
    float minax = (cx0 <= 0.f && cx1 >= 0.f) ? 0.f : fminf(fabsf(cx0), fabsf(cx1));
    float minay = (cy0 <= 0.f && cy1 >= 0.f) ? 0.f : fminf(fabsf(cy0), fabsf(cy1));
    float rmin2 = minax * minax + minay * minay;

    size_t oidx = ((size_t)b << 20) + ((size_t)yg << 10) + (size_t)xg;
    if (rmin2 > 1.000001f) { out[oidx] = 0.f; return; }

    // Uniform (SGPR) row pointer, bumped by RS per angle; per-lane index j is a
    // 32-bit VGPR -> global_load v, v_off, s[base] addressing. +GUARD bias keeps
    // all in-circle indices >= 0 so trunc == floor and fract matches. Pixels with
    // |T|>1 may read garbage inside ws (never OOB past ws: j in [-165,1285], and
    // OFF_XAF=1232 floats of tables precede xaf; tail slack proven in R1/R2 runs)
    // but those pixels are zeroed by the circle mask.
    const float* row = xaf + (size_t)b * (AA * RS);
    const float BIAS = 511.5f + (float)GUARD;   // 559.5
    float nuy = -uy;
    float acc = 0.f;

    #pragma unroll 4
    for (int a = 0; a < AA; ++a) {
        float2 cs = cst2[a];                       // uniform -> s_load_dwordx2
        float iy = fmaf(ux, cs.x, fmaf(nuy, cs.y, BIAS));
        int j = (int)iy;                           // trunc (== floor for iy>=0)
        float fy = fractf_(iy);
        float v0 = row[j];
        float v1 = row[j + 1];
        acc = fmaf(fy, v1 - v0, acc + v0);
        row += RS;
    }

    // bit-exact circle mask (pi/(2A) scale already folded into the filter)
    float r2 = __fadd_rn(__fmul_rn(ux, ux), __fmul_rn(uy, uy));
    out[oidx] = (r2 <= 1.0f) ? acc : 0.f;
}

extern "C" void kernel_launch(void* const* d_in, const int* in_sizes, int n_in,
                              void* d_out, int out_size, void* d_ws, size_t ws_size,
                              hipStream_t stream) {
    const float* x = (const float*)d_in[0];
    float* out = (float*)d_out;
    float* ws = (float*)d_ws;
    float* cg  = ws + OFF_CG;
    float* xaf = ws + OFF_XAF;

    hipLaunchKernelGGL(k_tables, dim3(1), dim3(512), 0, stream, ws);
    hipLaunchKernelGGL(k_filter, dim3(NCOL), dim3(64), 0, stream, x, cg, xaf);
    hipLaunchKernelGGL(k_bproj, dim3(64, 64, BB), dim3(256), 0, stream, ws, xaf, out);
}